// Round 9
// baseline (18397.333 us; speedup 1.0000x reference)
//
#include <hip/hip_runtime.h>
#include <math.h>

#pragma clang fp contract(off)

#define NB 4096
#define NS 512
#define NI 10
#define NH 20

#define MAIN_BLOCKS 256
#define ROWS_PB 16
#define MAIN_THREADS 320   // 20 t-groups * 16 rows
#define NWAVES 5

// ws byte offsets
#define OFF_GCNT 0         // u32[2048] arrival counters
#define OFF_GMAX 8192      // u32[2048] f32-bit amax slots
#define OFF_GRES 16384     // u32[2048] published result | 1<<31
#define OFF_WQ   24576     // f32 quantized weights: 800+1600+1280+2048+160

#define IDX_RELUH 1536
#define IDX_A1    1537
#define IDX_A2    1538
#define IDX_XMAX  1539

// ---- XLA-CPU f32 emulation ----
// Model: Eigen gemms (AVX, no FMA) => k-ascending mul+add dots. Jitted
// elementwise fusions contracted to FMA by host DAG (AllowFPOpFusion::Fast,
// single-use fmul rule). logistic HLO expanded as 0.5 + 0.5*tanh(0.5*x)
// (CPU LogisticExpander; gives the known exact-0/1 sigmoid saturation).
// Algebraic simplifier: divide-by-CONSTANT -> multiply-by-reciprocal
// (scale = max/n and quant_fixed's x/(1/n)); divide by runtime broadcast
// scalar (dynamic-scale codes) stays a true IEEE division.

// XLA CPU fast tanh (EmitFastTanh / Eigen ptanh), FMA-contracted Horner.
__device__ __forceinline__ float tanh_xla(float x) {
  float ax = fabsf(x);
  float cx = fminf(fmaxf(x, -7.90531110763549805f), 7.90531110763549805f);
  float x2 = cx * cx;
  float p = fmaf(-2.76076847742355e-16f, x2, 2.00018790482477e-13f);
  p = fmaf(p, x2, -8.60467152213735e-11f);
  p = fmaf(p, x2, 5.12229709037114e-08f);
  p = fmaf(p, x2, 1.48572235717979e-05f);
  p = fmaf(p, x2, 6.37261928875436e-04f);
  p = fmaf(p, x2, 4.89352455891786e-03f);
  p = cx * p;
  float q = fmaf(1.19825839466702e-06f, x2, 1.18534705686654e-04f);
  q = fmaf(q, x2, 2.26843463243900e-03f);
  q = fmaf(q, x2, 4.89352518554385e-03f);
  float t = p / q;
  return (ax < 0.0004f) ? x : t;
}

// logistic(x) = 0.5 + 0.5*tanh(0.5*x); final add+mul contracts to fma.
__device__ __forceinline__ float sigmoid_xla(float x) {
  float th = tanh_xla(0.5f * x);
  return fmaf(0.5f, th, 0.5f);
}

// quant+STE, dynamic scale: codes via TRUE division (runtime scalar divisor);
// diff = fmsub(r,s,x) [mul(r,s) single-use => fused]; out = x + diff (plain).
__device__ __forceinline__ float qste(float x, float s, float lo, float hi) {
  float r = rintf(x / s);
  r = fminf(fmaxf(r, lo), hi);
  float diff = fmaf(r, s, -x);
  return x + diff;
}

// quant+STE, constant scale: codes via reciprocal-multiply (div-by-const
// folded by algsimp); q = r*s; same STE fusion shape.
__device__ __forceinline__ float qste_fix(float x, float s, float rq, float lo, float hi) {
  float r = rintf(x * rq);
  r = fminf(fmaxf(r, lo), hi);
  float diff = fmaf(r, s, -x);
  return x + diff;
}

__device__ __forceinline__ float wave_max_f32(float v) {
#pragma unroll
  for (int o = 32; o; o >>= 1) v = fmaxf(v, __shfl_xor(v, o));
  return v;
}

// ---------------- pre: global amax of x ----------------
__global__ void k_amax_x(const float* __restrict__ x, unsigned* slot, long n4) {
  long i = (long)blockIdx.x * blockDim.x + threadIdx.x;
  long stride = (long)gridDim.x * blockDim.x;
  const float4* x4 = (const float4*)x;
  float m = 0.f;
  for (; i < n4; i += stride) {
    float4 v = x4[i];
    m = fmaxf(m, fmaxf(fmaxf(fabsf(v.x), fabsf(v.y)), fmaxf(fabsf(v.z), fabsf(v.w))));
  }
  m = wave_max_f32(m);
  __shared__ float red[8];
  int lane = threadIdx.x & 63, wv = threadIdx.x >> 6;
  if (!lane) red[wv] = m;
  __syncthreads();
  if (threadIdx.x == 0) {
    int nw = blockDim.x >> 6;
    for (int w = 1; w < nw; w++) m = fmaxf(m, red[w]);
    atomicMax(slot, __float_as_uint(m));
  }
}

// ---------------- pre: fake-quantize 5 weight tensors ----------------
__global__ void k_quant_w(const float* __restrict__ w_ih, const float* __restrict__ w_hh,
                          const float* __restrict__ w1, const float* __restrict__ w2,
                          const float* __restrict__ w3, void* wsv) {
  float* wihq = (float*)((char*)wsv + OFF_WQ);
  float* whhq = wihq + 800;
  float* w1q  = whhq + 1600;
  float* w2q  = w1q + 1280;
  float* w3q  = w2q + 2048;
  const float* src; float* dst; int n;
  switch (blockIdx.x) {
    case 0: src = w_ih; dst = wihq; n = 800;  break;
    case 1: src = w_hh; dst = whhq; n = 1600; break;
    case 2: src = w1;   dst = w1q;  n = 1280; break;
    case 3: src = w2;   dst = w2q;  n = 2048; break;
    default: src = w3;  dst = w3q;  n = 160;  break;
  }
  float m = 0.f;
  for (int i = threadIdx.x; i < n; i += blockDim.x) m = fmaxf(m, fabsf(src[i]));
  m = wave_max_f32(m);
  __shared__ float red[8];
  __shared__ float mg;
  int lane = threadIdx.x & 63, wv = threadIdx.x >> 6;
  if (!lane) red[wv] = m;
  __syncthreads();
  if (threadIdx.x == 0) {
    int nw = blockDim.x >> 6;
    for (int w = 1; w < nw; w++) m = fmaxf(m, red[w]);
    mg = m;
  }
  __syncthreads();
  float s = fmaxf(mg, 1e-8f) * (1.0f / 127.0f);   // div-by-const => recip-mul
  for (int i = threadIdx.x; i < n; i += blockDim.x) {
    dst[i] = qste(src[i], s, -127.0f, 127.0f);    // dynamic divisor: true div
  }
}

// ---------------- grid-wide f32 amax with spin barrier ----------------
__device__ __forceinline__ float grid_amax32(float v, int idx, unsigned* gcnt, unsigned* gmax,
                                             unsigned* gres, float* red, float* bc) {
  v = wave_max_f32(v);
  int lane = threadIdx.x & 63, wv = threadIdx.x >> 6;
  if (!lane) red[wv] = v;
  __syncthreads();
  if (threadIdx.x == 0) {
    float m = red[0];
#pragma unroll
    for (int w = 1; w < NWAVES; w++) m = fmaxf(m, red[w]);
    atomicMax(&gmax[idx], __float_as_uint(m));
    unsigned old = __hip_atomic_fetch_add(&gcnt[idx], 1u, __ATOMIC_ACQ_REL, __HIP_MEMORY_SCOPE_AGENT);
    if (old == MAIN_BLOCKS - 1) {
      unsigned mb = __hip_atomic_load(&gmax[idx], __ATOMIC_RELAXED, __HIP_MEMORY_SCOPE_AGENT);
      __hip_atomic_store(&gres[idx], mb | 0x80000000u, __ATOMIC_RELEASE, __HIP_MEMORY_SCOPE_AGENT);
    }
    unsigned r;
    do {
      r = __hip_atomic_load(&gres[idx], __ATOMIC_ACQUIRE, __HIP_MEMORY_SCOPE_AGENT);
      if (!r) __builtin_amdgcn_s_sleep(2);
    } while (!r);
    *bc = __uint_as_float(r & 0x7FFFFFFFu);
  }
  __syncthreads();
  return *bc;
}

// ---------------- persistent f32 quantized LSTM + MLP head ----------------
__global__ void __launch_bounds__(MAIN_THREADS) k_lstm(
    const float* __restrict__ x, const float* __restrict__ b_ih,
    const float* __restrict__ b_hh, const float* __restrict__ b1,
    const float* __restrict__ b2, const float* __restrict__ b3,
    void* wsv, float* __restrict__ out) {
  unsigned* gcnt = (unsigned*)((char*)wsv + OFF_GCNT);
  unsigned* gmax = (unsigned*)((char*)wsv + OFF_GMAX);
  unsigned* gres = (unsigned*)((char*)wsv + OFF_GRES);
  const float* wihq = (const float*)((char*)wsv + OFF_WQ);
  const float* whhq = wihq + 800;
  const float* w1q  = whhq + 1600;
  const float* w2q  = w1q + 1280;
  const float* w3q  = w2q + 2048;

  __shared__ float whh_l[NH][80];       // [j][g] transposed for broadcast
  __shared__ float wih_l[NI][80];       // [i][g]
  __shared__ float w1_l[64 * NH];
  __shared__ float w2_l[32 * 64];
  __shared__ float w3_l[5 * 32];
  __shared__ float xq_l[ROWS_PB][321];  // 32-step chunk of STE'd xq (padded)
  __shared__ float hrow[ROWS_PB][NH + 1];
  __shared__ float a1row[ROWS_PB][65];
  __shared__ float a2row[ROWS_PB][33];
  __shared__ float red[NWAVES];
  __shared__ float bc;

  const int tid = threadIdx.x;
  const int t  = tid >> 4;    // hidden unit 0..19
  const int rl = tid & 15;    // row-in-block 0..15

  for (int e = tid; e < 80 * NH; e += MAIN_THREADS) whh_l[e % NH][e / NH] = whhq[e];
  for (int e = tid; e < 80 * NI; e += MAIN_THREADS) wih_l[e % NI][e / NI] = wihq[e];
  for (int e = tid; e < 64 * NH; e += MAIN_THREADS) w1_l[e] = w1q[e];
  for (int e = tid; e < 32 * 64; e += MAIN_THREADS) w2_l[e] = w2q[e];
  for (int e = tid; e < 5 * 32; e += MAIN_THREADS) w3_l[e] = w3q[e];

  float bih0 = b_ih[t],      bhh0 = b_hh[t];
  float bih1 = b_ih[20 + t], bhh1 = b_hh[20 + t];
  float bih2 = b_ih[40 + t], bhh2 = b_hh[40 + t];
  float bih3 = b_ih[60 + t], bhh3 = b_hh[60 + t];

  const float sx  = fmaxf(__uint_as_float(gmax[IDX_XMAX]), 1e-8f) * (1.0f / 127.0f);
  const float s63 = (float)(1.0 / 63.0);
  const float s31 = (float)(1.0 / 31.0);
  const float rq63 = 1.0f / s63;   // algsimp: x/(1/63) => x * fl(1/fl(1/63))
  const float rq31 = 1.0f / s31;

  float c = 0.0f, h = 0.0f;
  hrow[rl][t] = 0.0f;
  __syncthreads();

  for (int s = 0; s < NS; s++) {
    if ((s & 31) == 0) {
      // stage 32 steps of STE'd quantized x (true-division codes)
      for (int e = tid; e < ROWS_PB * 320; e += MAIN_THREADS) {
        int r = e / 320, off = e % 320;
        float raw = x[((long)blockIdx.x * ROWS_PB + r) * (NS * NI) + (long)s * NI + off];
        xq_l[r][off] = qste(raw, sx, -127.0f, 127.0f);
      }
    }
    __syncthreads();

    // gates = ((xq.Wih + b_ih) + b_hh) + h.Whh — Eigen AVX no-FMA: k-asc mul+add
    float ax0 = 0.f, ax1 = 0.f, ax2 = 0.f, ax3 = 0.f;
    int xo = (s & 31) * NI;
#pragma unroll
    for (int i = 0; i < NI; i++) {
      float xv = xq_l[rl][xo + i];
      ax0 = ax0 + xv * wih_l[i][t];
      ax1 = ax1 + xv * wih_l[i][20 + t];
      ax2 = ax2 + xv * wih_l[i][40 + t];
      ax3 = ax3 + xv * wih_l[i][60 + t];
    }
    float ah0 = 0.f, ah1 = 0.f, ah2 = 0.f, ah3 = 0.f;
#pragma unroll
    for (int j = 0; j < NH; j++) {
      float hv = hrow[rl][j];
      ah0 = ah0 + hv * whh_l[j][t];
      ah1 = ah1 + hv * whh_l[j][20 + t];
      ah2 = ah2 + hv * whh_l[j][40 + t];
      ah3 = ah3 + hv * whh_l[j][60 + t];
    }
    float g0 = ((ax0 + bih0) + bhh0) + ah0;
    float g1 = ((ax1 + bih1) + bhh1) + ah1;
    float g2 = ((ax2 + bih2) + bhh2) + ah2;
    float g3 = ((ax3 + bih3) + bhh3) + ah3;

    // phase 0: gate accumulator quant (6-bit signed, dynamic)
    float m0 = fmaxf(fmaxf(fabsf(g0), fabsf(g1)), fmaxf(fabsf(g2), fabsf(g3)));
    float M1 = grid_amax32(m0, 3 * s + 0, gcnt, gmax, gres, red, &bc);
    float sc1 = fmaxf(M1, 1e-8f) * (1.0f / 31.0f);
    g0 = qste(g0, sc1, -31.0f, 31.0f);
    g1 = qste(g1, sc1, -31.0f, 31.0f);
    g2 = qste(g2, sc1, -31.0f, 31.0f);
    g3 = qste(g3, sc1, -31.0f, 31.0f);

    float ig = qste_fix(sigmoid_xla(g0), s63, rq63, 0.0f, 63.0f);
    float fg = qste_fix(sigmoid_xla(g1), s63, rq63, 0.0f, 63.0f);
    float gg = qste_fix(tanh_xla(g2),    s31, rq31, -31.0f, 31.0f);
    float og = qste_fix(sigmoid_xla(g3), s63, rq63, 0.0f, 63.0f);

    // craw = fma(f, c, fl(i*g)) — DAG fuses the first (single-use) fmul operand
    float craw = fmaf(fg, c, ig * gg);

    // phase 1: cell state quant (craw materialized => STE outer add plain)
    float M2 = grid_amax32(fabsf(craw), 3 * s + 1, gcnt, gmax, gres, red, &bc);
    float sc2 = fmaxf(M2, 1e-8f) * (1.0f / 31.0f);
    c = qste(craw, sc2, -31.0f, 31.0f);

    float th = qste_fix(tanh_xla(c), s31, rq31, -31.0f, 31.0f);

    // h-quant: hraw materialized by the max-reduce => no outer-add fusion
    float hraw = og * th;
    float M3 = grid_amax32(fabsf(hraw), 3 * s + 2, gcnt, gmax, gres, red, &bc);
    float sc3 = fmaxf(M3, 1e-8f) * (1.0f / 127.0f);
    h = qste(hraw, sc3, -127.0f, 127.0f);

    hrow[rl][t] = h;
  }

  // ---- MLP head ----
  float rh = fmaxf(h, 0.0f);
  float Mr = grid_amax32(rh, IDX_RELUH, gcnt, gmax, gres, red, &bc);
  float sr = fmaxf(Mr, 1e-8f) * (1.0f / 63.0f);
  hrow[rl][t] = qste(rh, sr, 0.0f, 63.0f);
  __syncthreads();

  // layer 1: 16 rows x 64 (Eigen no-FMA: k-asc mul+add)
  float m1 = 0.0f;
  for (int e = tid; e < ROWS_PB * 64; e += MAIN_THREADS) {
    int r = e >> 6, o = e & 63;
    float acc = 0.f;
#pragma unroll
    for (int k = 0; k < NH; k++) acc = acc + hrow[r][k] * w1_l[o * NH + k];
    acc = acc + b1[o];
    float rv = fmaxf(acc, 0.0f);
    a1row[r][o] = rv;
    m1 = fmaxf(m1, rv);
  }
  float Ma = grid_amax32(m1, IDX_A1, gcnt, gmax, gres, red, &bc);
  float s1 = fmaxf(Ma, 1e-8f) * (1.0f / 63.0f);
  for (int e = tid; e < ROWS_PB * 64; e += MAIN_THREADS) {
    int r = e >> 6, o = e & 63;
    a1row[r][o] = qste(a1row[r][o], s1, 0.0f, 63.0f);
  }
  __syncthreads();

  // layer 2: 16 rows x 32
  float m2 = 0.0f;
  for (int e = tid; e < ROWS_PB * 32; e += MAIN_THREADS) {
    int r = e >> 5, o = e & 31;
    float acc = 0.f;
#pragma unroll
    for (int k = 0; k < 64; k++) acc = acc + a1row[r][k] * w2_l[o * 64 + k];
    acc = acc + b2[o];
    float rv = fmaxf(acc, 0.0f);
    a2row[r][o] = rv;
    m2 = fmaxf(m2, rv);
  }
  float Mb = grid_amax32(m2, IDX_A2, gcnt, gmax, gres, red, &bc);
  float s2 = fmaxf(Mb, 1e-8f) * (1.0f / 63.0f);
  for (int e = tid; e < ROWS_PB * 32; e += MAIN_THREADS) {
    int r = e >> 5, o = e & 31;
    a2row[r][o] = qste(a2row[r][o], s2, 0.0f, 63.0f);
  }
  __syncthreads();

  // layer 3: 16 rows x 5 -> out
  for (int e = tid; e < ROWS_PB * 5; e += MAIN_THREADS) {
    int r = e / 5, o = e % 5;
    float acc = 0.f;
#pragma unroll
    for (int k = 0; k < 32; k++) acc = acc + a2row[r][k] * w3_l[o * 32 + k];
    acc = acc + b3[o];
    out[((long)blockIdx.x * ROWS_PB + r) * 5 + o] = acc;
  }
}

extern "C" void kernel_launch(void* const* d_in, const int* in_sizes, int n_in,
                              void* d_out, int out_size, void* d_ws, size_t ws_size,
                              hipStream_t stream) {
  const float* x    = (const float*)d_in[0];
  const float* W_ih = (const float*)d_in[1];
  const float* W_hh = (const float*)d_in[2];
  const float* b_ih = (const float*)d_in[3];
  const float* b_hh = (const float*)d_in[4];
  const float* W1   = (const float*)d_in[5];
  const float* b1   = (const float*)d_in[6];
  const float* W2   = (const float*)d_in[7];
  const float* b2   = (const float*)d_in[8];
  const float* W3   = (const float*)d_in[9];
  const float* b3   = (const float*)d_in[10];
  float* out = (float*)d_out;

  // zero sync state (gcnt+gmax+gres); replayed every graph launch
  hipMemsetAsync(d_ws, 0, 24576, stream);

  unsigned* xslot = (unsigned*)((char*)d_ws + OFF_GMAX) + IDX_XMAX;
  k_amax_x<<<1024, 256, 0, stream>>>(x, xslot, (long)NB * NS * NI / 4);
  k_quant_w<<<5, 256, 0, stream>>>(W_ih, W_hh, W1, W2, W3, d_ws);
  k_lstm<<<MAIN_BLOCKS, MAIN_THREADS, 0, stream>>>(x, b_ih, b_hh, b1, b2, b3, d_ws, out);
}

// Round 10
// 3985.540 us; speedup vs baseline: 4.6160x; 4.6160x over previous
//
#include <hip/hip_runtime.h>
#include <math.h>

#pragma clang fp contract(off)

#define NB 4096
#define NS 512
#define NI 10
#define NH 20

#define MAIN_BLOCKS 256
#define ROWS_PB 16
#define MAIN_THREADS 320   // 20 t-groups * 16 rows
#define NWAVES 5

// ws byte offsets
#define OFF_GRES 0         // u32[2048]: published result | 1<<31, per phase; [1539] = xmax bits
#define OFF_SLOT 8192      // u64[256]: per-block {tag:32 = phase+1, max f32 bits:32}
#define OFF_WQ   16384     // f32 quantized weights: 800+1600+1280+2048+160

#define IDX_RELUH 1536
#define IDX_A1    1537
#define IDX_A2    1538
#define IDX_XMAX  1539

// ---- XLA-CPU f32 emulation (verified bit-exact in R9) ----
// Eigen gemms (AVX, no FMA) => k-ascending mul+add dots. Jitted elementwise
// fusions FMA-contracted (single-use fmul rule). logistic = 0.5+0.5*tanh(0.5x).
// Div-by-constant => recip-mul; div by runtime broadcast scalar stays true div.

__device__ __forceinline__ float tanh_xla(float x) {
  float ax = fabsf(x);
  float cx = fminf(fmaxf(x, -7.90531110763549805f), 7.90531110763549805f);
  float x2 = cx * cx;
  float p = fmaf(-2.76076847742355e-16f, x2, 2.00018790482477e-13f);
  p = fmaf(p, x2, -8.60467152213735e-11f);
  p = fmaf(p, x2, 5.12229709037114e-08f);
  p = fmaf(p, x2, 1.48572235717979e-05f);
  p = fmaf(p, x2, 6.37261928875436e-04f);
  p = fmaf(p, x2, 4.89352455891786e-03f);
  p = cx * p;
  float q = fmaf(1.19825839466702e-06f, x2, 1.18534705686654e-04f);
  q = fmaf(q, x2, 2.26843463243900e-03f);
  q = fmaf(q, x2, 4.89352518554385e-03f);
  float t = p / q;
  return (ax < 0.0004f) ? x : t;
}

__device__ __forceinline__ float sigmoid_xla(float x) {
  float th = tanh_xla(0.5f * x);
  return fmaf(0.5f, th, 0.5f);
}

// dynamic scale: true-division codes; STE diff fused (fmsub), outer add plain
__device__ __forceinline__ float qste(float x, float s, float lo, float hi) {
  float r = rintf(x / s);
  r = fminf(fmaxf(r, lo), hi);
  float diff = fmaf(r, s, -x);
  return x + diff;
}

// constant scale: recip-mul codes (algsimp)
__device__ __forceinline__ float qste_fix(float x, float s, float rq, float lo, float hi) {
  float r = rintf(x * rq);
  r = fminf(fmaxf(r, lo), hi);
  float diff = fmaf(r, s, -x);
  return x + diff;
}

__device__ __forceinline__ float wave_max_f32(float v) {
#pragma unroll
  for (int o = 32; o; o >>= 1) v = fmaxf(v, __shfl_xor(v, o));
  return v;
}

// ---------------- pre: global amax of x ----------------
__global__ void k_amax_x(const float* __restrict__ x, unsigned* slot, long n4) {
  long i = (long)blockIdx.x * blockDim.x + threadIdx.x;
  long stride = (long)gridDim.x * blockDim.x;
  const float4* x4 = (const float4*)x;
  float m = 0.f;
  for (; i < n4; i += stride) {
    float4 v = x4[i];
    m = fmaxf(m, fmaxf(fmaxf(fabsf(v.x), fabsf(v.y)), fmaxf(fabsf(v.z), fabsf(v.w))));
  }
  m = wave_max_f32(m);
  __shared__ float red[8];
  int lane = threadIdx.x & 63, wv = threadIdx.x >> 6;
  if (!lane) red[wv] = m;
  __syncthreads();
  if (threadIdx.x == 0) {
    int nw = blockDim.x >> 6;
    for (int w = 1; w < nw; w++) m = fmaxf(m, red[w]);
    atomicMax(slot, __float_as_uint(m));
  }
}

// ---------------- pre: fake-quantize 5 weight tensors ----------------
__global__ void k_quant_w(const float* __restrict__ w_ih, const float* __restrict__ w_hh,
                          const float* __restrict__ w1, const float* __restrict__ w2,
                          const float* __restrict__ w3, void* wsv) {
  float* wihq = (float*)((char*)wsv + OFF_WQ);
  float* whhq = wihq + 800;
  float* w1q  = whhq + 1600;
  float* w2q  = w1q + 1280;
  float* w3q  = w2q + 2048;
  const float* src; float* dst; int n;
  switch (blockIdx.x) {
    case 0: src = w_ih; dst = wihq; n = 800;  break;
    case 1: src = w_hh; dst = whhq; n = 1600; break;
    case 2: src = w1;   dst = w1q;  n = 1280; break;
    case 3: src = w2;   dst = w2q;  n = 2048; break;
    default: src = w3;  dst = w3q;  n = 160;  break;
  }
  float m = 0.f;
  for (int i = threadIdx.x; i < n; i += blockDim.x) m = fmaxf(m, fabsf(src[i]));
  m = wave_max_f32(m);
  __shared__ float red[8];
  __shared__ float mg;
  int lane = threadIdx.x & 63, wv = threadIdx.x >> 6;
  if (!lane) red[wv] = m;
  __syncthreads();
  if (threadIdx.x == 0) {
    int nw = blockDim.x >> 6;
    for (int w = 1; w < nw; w++) m = fmaxf(m, red[w]);
    mg = m;
  }
  __syncthreads();
  float s = fmaxf(mg, 1e-8f) * (1.0f / 127.0f);
  for (int i = threadIdx.x; i < n; i += blockDim.x) {
    dst[i] = qste(src[i], s, -127.0f, 127.0f);
  }
}

// ---------------- grid-wide f32 amax: slots + reducer wave, all-relaxed ----------------
// Each block stores {tag,max} to its own slot. Block 0 wave 0 polls all 256
// slots, reduces, publishes to gres[idx] with bit31 set. All data travels in
// the atomic words themselves => no fences needed. Tags strictly increase =>
// no ABA. Slots+gres memset per launch.
__device__ __forceinline__ float grid_amax32(float v, int idx,
    unsigned long long* slots, unsigned* gres, float* red, float* bc) {
  v = wave_max_f32(v);
  int lane = threadIdx.x & 63, wv = threadIdx.x >> 6;
  if (!lane) red[wv] = v;
  __syncthreads();
  if (threadIdx.x < 64) {
    float m = red[0];
#pragma unroll
    for (int w = 1; w < NWAVES; w++) m = fmaxf(m, red[w]);
    unsigned bits = __float_as_uint(m);
    if (threadIdx.x == 0) {
      unsigned long long word = (((unsigned long long)(unsigned)(idx + 1)) << 32) | bits;
      __hip_atomic_store(&slots[blockIdx.x], word, __ATOMIC_RELAXED, __HIP_MEMORY_SCOPE_AGENT);
    }
    if (blockIdx.x == 0) {
      unsigned tag = (unsigned)(idx + 1);
      int l = threadIdx.x;
      unsigned long long v0, v1, v2, v3;
      for (;;) {
        v0 = __hip_atomic_load(&slots[l],       __ATOMIC_RELAXED, __HIP_MEMORY_SCOPE_AGENT);
        v1 = __hip_atomic_load(&slots[l + 64],  __ATOMIC_RELAXED, __HIP_MEMORY_SCOPE_AGENT);
        v2 = __hip_atomic_load(&slots[l + 128], __ATOMIC_RELAXED, __HIP_MEMORY_SCOPE_AGENT);
        v3 = __hip_atomic_load(&slots[l + 192], __ATOMIC_RELAXED, __HIP_MEMORY_SCOPE_AGENT);
        bool ok = ((unsigned)(v0 >> 32) == tag) && ((unsigned)(v1 >> 32) == tag) &&
                  ((unsigned)(v2 >> 32) == tag) && ((unsigned)(v3 >> 32) == tag);
        if (__all(ok)) break;
      }
      unsigned mx = max(max((unsigned)v0, (unsigned)v1), max((unsigned)v2, (unsigned)v3));
#pragma unroll
      for (int o = 32; o; o >>= 1) {
        unsigned other = (unsigned)__shfl_xor((int)mx, o);
        mx = mx > other ? mx : other;
      }
      if (threadIdx.x == 0)
        __hip_atomic_store(&gres[idx], mx | 0x80000000u, __ATOMIC_RELAXED, __HIP_MEMORY_SCOPE_AGENT);
    }
  }
  if (threadIdx.x == 0) {
    unsigned r;
    do {
      r = __hip_atomic_load(&gres[idx], __ATOMIC_RELAXED, __HIP_MEMORY_SCOPE_AGENT);
      if (!r) __builtin_amdgcn_s_sleep(1);
    } while (!r);
    *bc = __uint_as_float(r & 0x7FFFFFFFu);
  }
  __syncthreads();
  return *bc;
}

// ---------------- persistent f32 quantized LSTM + MLP head ----------------
__global__ void __launch_bounds__(MAIN_THREADS) k_lstm(
    const float* __restrict__ x, const float* __restrict__ b_ih,
    const float* __restrict__ b_hh, const float* __restrict__ b1,
    const float* __restrict__ b2, const float* __restrict__ b3,
    void* wsv, float* __restrict__ out) {
  unsigned* gres = (unsigned*)((char*)wsv + OFF_GRES);
  unsigned long long* slots = (unsigned long long*)((char*)wsv + OFF_SLOT);
  const float* wihq = (const float*)((char*)wsv + OFF_WQ);
  const float* whhq = wihq + 800;
  const float* w1q  = whhq + 1600;
  const float* w2q  = w1q + 1280;
  const float* w3q  = w2q + 2048;

  __shared__ float whh_l[NH][80];       // [j][g] transposed for broadcast
  __shared__ float wih_l[NI][80];       // [i][g]
  __shared__ float w1_l[64 * NH];
  __shared__ float w2_l[32 * 64];
  __shared__ float w3_l[5 * 32];
  __shared__ float xq_l[ROWS_PB][321];  // 32-step chunk of STE'd xq (padded)
  __shared__ float hrow[ROWS_PB][NH + 1];
  __shared__ float a1row[ROWS_PB][65];
  __shared__ float a2row[ROWS_PB][33];
  __shared__ float red[NWAVES];
  __shared__ float bc;

  const int tid = threadIdx.x;
  const int t  = tid >> 4;    // hidden unit 0..19
  const int rl = tid & 15;    // row-in-block 0..15

  for (int e = tid; e < 80 * NH; e += MAIN_THREADS) whh_l[e % NH][e / NH] = whhq[e];
  for (int e = tid; e < 80 * NI; e += MAIN_THREADS) wih_l[e % NI][e / NI] = wihq[e];
  for (int e = tid; e < 64 * NH; e += MAIN_THREADS) w1_l[e] = w1q[e];
  for (int e = tid; e < 32 * 64; e += MAIN_THREADS) w2_l[e] = w2q[e];
  for (int e = tid; e < 5 * 32; e += MAIN_THREADS) w3_l[e] = w3q[e];

  float bih0 = b_ih[t],      bhh0 = b_hh[t];
  float bih1 = b_ih[20 + t], bhh1 = b_hh[20 + t];
  float bih2 = b_ih[40 + t], bhh2 = b_hh[40 + t];
  float bih3 = b_ih[60 + t], bhh3 = b_hh[60 + t];

  const float sx  = fmaxf(__uint_as_float(gres[IDX_XMAX]), 1e-8f) * (1.0f / 127.0f);
  const float s63 = (float)(1.0 / 63.0);
  const float s31 = (float)(1.0 / 31.0);
  const float rq63 = 1.0f / s63;
  const float rq31 = 1.0f / s31;

  float c = 0.0f, h = 0.0f;
  hrow[rl][t] = 0.0f;
  __syncthreads();

  for (int s = 0; s < NS; s++) {
    if ((s & 31) == 0) {
      for (int e = tid; e < ROWS_PB * 320; e += MAIN_THREADS) {
        int r = e / 320, off = e % 320;
        float raw = x[((long)blockIdx.x * ROWS_PB + r) * (NS * NI) + (long)s * NI + off];
        xq_l[r][off] = qste(raw, sx, -127.0f, 127.0f);
      }
    }
    __syncthreads();

    // gates = ((xq.Wih + b_ih) + b_hh) + h.Whh — k-ascending mul+add (no FMA)
    float ax0 = 0.f, ax1 = 0.f, ax2 = 0.f, ax3 = 0.f;
    int xo = (s & 31) * NI;
#pragma unroll
    for (int i = 0; i < NI; i++) {
      float xv = xq_l[rl][xo + i];
      ax0 = ax0 + xv * wih_l[i][t];
      ax1 = ax1 + xv * wih_l[i][20 + t];
      ax2 = ax2 + xv * wih_l[i][40 + t];
      ax3 = ax3 + xv * wih_l[i][60 + t];
    }
    float ah0 = 0.f, ah1 = 0.f, ah2 = 0.f, ah3 = 0.f;
#pragma unroll
    for (int j = 0; j < NH; j++) {
      float hv = hrow[rl][j];
      ah0 = ah0 + hv * whh_l[j][t];
      ah1 = ah1 + hv * whh_l[j][20 + t];
      ah2 = ah2 + hv * whh_l[j][40 + t];
      ah3 = ah3 + hv * whh_l[j][60 + t];
    }
    float g0 = ((ax0 + bih0) + bhh0) + ah0;
    float g1 = ((ax1 + bih1) + bhh1) + ah1;
    float g2 = ((ax2 + bih2) + bhh2) + ah2;
    float g3 = ((ax3 + bih3) + bhh3) + ah3;

    // phase 0: gate accumulator quant (6-bit signed, dynamic)
    float m0 = fmaxf(fmaxf(fabsf(g0), fabsf(g1)), fmaxf(fabsf(g2), fabsf(g3)));
    float M1 = grid_amax32(m0, 3 * s + 0, slots, gres, red, &bc);
    float sc1 = fmaxf(M1, 1e-8f) * (1.0f / 31.0f);
    g0 = qste(g0, sc1, -31.0f, 31.0f);
    g1 = qste(g1, sc1, -31.0f, 31.0f);
    g2 = qste(g2, sc1, -31.0f, 31.0f);
    g3 = qste(g3, sc1, -31.0f, 31.0f);

    float ig = qste_fix(sigmoid_xla(g0), s63, rq63, 0.0f, 63.0f);
    float fg = qste_fix(sigmoid_xla(g1), s63, rq63, 0.0f, 63.0f);
    float gg = qste_fix(tanh_xla(g2),    s31, rq31, -31.0f, 31.0f);
    float og = qste_fix(sigmoid_xla(g3), s63, rq63, 0.0f, 63.0f);

    float craw = fmaf(fg, c, ig * gg);

    // phase 1: cell state quant
    float M2 = grid_amax32(fabsf(craw), 3 * s + 1, slots, gres, red, &bc);
    float sc2 = fmaxf(M2, 1e-8f) * (1.0f / 31.0f);
    c = qste(craw, sc2, -31.0f, 31.0f);

    float th = qste_fix(tanh_xla(c), s31, rq31, -31.0f, 31.0f);

    // phase 2: hidden io quant
    float hraw = og * th;
    float M3 = grid_amax32(fabsf(hraw), 3 * s + 2, slots, gres, red, &bc);
    float sc3 = fmaxf(M3, 1e-8f) * (1.0f / 127.0f);
    h = qste(hraw, sc3, -127.0f, 127.0f);

    hrow[rl][t] = h;
  }

  // ---- MLP head ----
  float rh = fmaxf(h, 0.0f);
  float Mr = grid_amax32(rh, IDX_RELUH, slots, gres, red, &bc);
  float sr = fmaxf(Mr, 1e-8f) * (1.0f / 63.0f);
  hrow[rl][t] = qste(rh, sr, 0.0f, 63.0f);
  __syncthreads();

  // layer 1: 16 rows x 64 (mul+add k-ascending)
  float m1 = 0.0f;
  for (int e = tid; e < ROWS_PB * 64; e += MAIN_THREADS) {
    int r = e >> 6, o = e & 63;
    float acc = 0.f;
#pragma unroll
    for (int k = 0; k < NH; k++) acc = acc + hrow[r][k] * w1_l[o * NH + k];
    acc = acc + b1[o];
    float rv = fmaxf(acc, 0.0f);
    a1row[r][o] = rv;
    m1 = fmaxf(m1, rv);
  }
  float Ma = grid_amax32(m1, IDX_A1, slots, gres, red, &bc);
  float s1 = fmaxf(Ma, 1e-8f) * (1.0f / 63.0f);
  for (int e = tid; e < ROWS_PB * 64; e += MAIN_THREADS) {
    int r = e >> 6, o = e & 63;
    a1row[r][o] = qste(a1row[r][o], s1, 0.0f, 63.0f);
  }
  __syncthreads();

  // layer 2: 16 rows x 32
  float m2 = 0.0f;
  for (int e = tid; e < ROWS_PB * 32; e += MAIN_THREADS) {
    int r = e >> 5, o = e & 31;
    float acc = 0.f;
#pragma unroll
    for (int k = 0; k < 64; k++) acc = acc + a1row[r][k] * w2_l[o * 64 + k];
    acc = acc + b2[o];
    float rv = fmaxf(acc, 0.0f);
    a2row[r][o] = rv;
    m2 = fmaxf(m2, rv);
  }
  float Mb = grid_amax32(m2, IDX_A2, slots, gres, red, &bc);
  float s2 = fmaxf(Mb, 1e-8f) * (1.0f / 63.0f);
  for (int e = tid; e < ROWS_PB * 32; e += MAIN_THREADS) {
    int r = e >> 5, o = e & 31;
    a2row[r][o] = qste(a2row[r][o], s2, 0.0f, 63.0f);
  }
  __syncthreads();

  // layer 3: 16 rows x 5 -> out
  for (int e = tid; e < ROWS_PB * 5; e += MAIN_THREADS) {
    int r = e / 5, o = e % 5;
    float acc = 0.f;
#pragma unroll
    for (int k = 0; k < 32; k++) acc = acc + a2row[r][k] * w3_l[o * 32 + k];
    acc = acc + b3[o];
    out[((long)blockIdx.x * ROWS_PB + r) * 5 + o] = acc;
  }
}

extern "C" void kernel_launch(void* const* d_in, const int* in_sizes, int n_in,
                              void* d_out, int out_size, void* d_ws, size_t ws_size,
                              hipStream_t stream) {
  const float* x    = (const float*)d_in[0];
  const float* W_ih = (const float*)d_in[1];
  const float* W_hh = (const float*)d_in[2];
  const float* b_ih = (const float*)d_in[3];
  const float* b_hh = (const float*)d_in[4];
  const float* W1   = (const float*)d_in[5];
  const float* b1   = (const float*)d_in[6];
  const float* W2   = (const float*)d_in[7];
  const float* b2   = (const float*)d_in[8];
  const float* W3   = (const float*)d_in[9];
  const float* b3   = (const float*)d_in[10];
  float* out = (float*)d_out;

  // zero gres (8KB) + slots (2KB @ 8192): replayed every graph launch
  hipMemsetAsync(d_ws, 0, 16384, stream);

  unsigned* xslot = (unsigned*)((char*)d_ws + OFF_GRES) + IDX_XMAX;
  k_amax_x<<<1024, 256, 0, stream>>>(x, xslot, (long)NB * NS * NI / 4);
  k_quant_w<<<5, 256, 0, stream>>>(W_ih, W_hh, W1, W2, W3, d_ws);
  k_lstm<<<MAIN_BLOCKS, MAIN_THREADS, 0, stream>>>(x, b_ih, b_hh, b1, b2, b3, d_ws, out);
}